// Round 1
// baseline (563.759 us; speedup 1.0000x reference)
//
#include <hip/hip_runtime.h>
#include <hip/hip_bf16.h>

#define C_IN 64
#define H_IN 512
#define W_IN 512
#define D_OUT 128
#define OH 510
#define OW 510
#define PXT 64      // output pixels per block (one row segment)
#define XT 8        // ceil(510/64)
#define TCOL 66     // PXT + 2 halo
#define TCPAD 72    // c-dim padded 64 -> 72 (144B px stride: conflict-free b128)

typedef __bf16 bf16x8 __attribute__((ext_vector_type(8)));
typedef float  f32x4  __attribute__((ext_vector_type(4)));

// Reorder kernels [D][C][3][3] fp32 -> Wt[kpos][d][c] bf16 (contiguous c for A-frags)
__global__ void prep_weights(const float* __restrict__ w, __bf16* __restrict__ wt) {
    int i = blockIdx.x * blockDim.x + threadIdx.x;
    if (i >= 9 * D_OUT * C_IN) return;
    int c    = i & 63;
    int d    = (i >> 6) & 127;
    int kpos = i >> 13;                 // 128*64 = 8192 per kpos
    wt[i] = (__bf16)w[((d * C_IN) + c) * 9 + kpos];
}

__global__ __launch_bounds__(256, 4)
void conv_bias_kernel(const float* __restrict__ in, const __bf16* __restrict__ wt,
                      const float* __restrict__ bias, float* __restrict__ out) {
    __shared__ __bf16 tile[3 * TCOL * TCPAD];

    const int b  = blockIdx.x;
    const int y  = b >> 3;              // output row
    const int x0 = (b & 7) * PXT;       // output col base

    const int tid = threadIdx.x;

    // ---- stage input tile: rows y..y+2, cols x0..x0+65 (clamped), all 64 ch, fp32->bf16
    for (int idx = tid; idx < 3 * TCOL * C_IN; idx += 256) {
        int col = idx % TCOL;
        int t   = idx / TCOL;
        int r   = t % 3;
        int c   = t / 3;
        int gx  = x0 + col;
        if (gx > W_IN - 1) gx = W_IN - 1;           // clamp; only feeds masked outputs
        float v = in[(c * H_IN + (y + r)) * W_IN + gx];
        tile[(r * TCOL + col) * TCPAD + c] = (__bf16)v;
    }
    __syncthreads();

    const int wave   = tid >> 6;
    const int lane   = tid & 63;
    const int l15    = lane & 15;
    const int quad   = lane >> 4;
    const int px_base = wave * 16;      // each wave: 16 px, full 128 d

    f32x4 acc[8];
#pragma unroll
    for (int i = 0; i < 8; i++) acc[i] = (f32x4){0.f, 0.f, 0.f, 0.f};

#pragma unroll
    for (int kpos = 0; kpos < 9; kpos++) {
        const int ky = kpos / 3, kx = kpos % 3;
#pragma unroll
        for (int ch = 0; ch < 2; ch++) {
            const int c0 = ch * 32;
            // B frag (K=32 x N=16): lane holds col n=l15, k = quad*8 + j  -> c = c0+quad*8+j
            const __bf16* bptr = &tile[(ky * TCOL + px_base + l15 + kx) * TCPAD + c0 + quad * 8];
            bf16x8 bfrag = *(const bf16x8*)bptr;
            // A frags (M=16 x K=32): lane holds row m=l15 (d), k = quad*8 + j
            const __bf16* aptr = wt + (size_t)kpos * D_OUT * C_IN + l15 * C_IN + c0 + quad * 8;
#pragma unroll
            for (int ds = 0; ds < 8; ds++) {
                bf16x8 afrag = *(const bf16x8*)(aptr + ds * 16 * C_IN);
                acc[ds] = __builtin_amdgcn_mfma_f32_16x16x32_bf16(afrag, bfrag, acc[ds], 0, 0, 0);
            }
        }
    }

    // ---- epilogue: C/D layout col=lane&15 (px), row=quad*4+reg (d); fuse bias
    const int gx = x0 + px_base + l15;
    if (gx < OW) {
#pragma unroll
        for (int ds = 0; ds < 8; ds++) {
            const int dbase = ds * 16 + quad * 4;
#pragma unroll
            for (int r = 0; r < 4; r++) {
                const size_t o = ((size_t)(dbase + r) * OH + y) * OW + gx;
                out[o] = acc[ds][r] + bias[o];
            }
        }
    }
}

extern "C" void kernel_launch(void* const* d_in, const int* in_sizes, int n_in,
                              void* d_out, int out_size, void* d_ws, size_t ws_size,
                              hipStream_t stream) {
    const float* in   = (const float*)d_in[0];
    const float* w    = (const float*)d_in[1];
    const float* bias = (const float*)d_in[2];
    float* out = (float*)d_out;
    __bf16* wt = (__bf16*)d_ws;   // 9*128*64*2 = 147456 bytes

    prep_weights<<<(9 * D_OUT * C_IN + 255) / 256, 256, 0, stream>>>(w, wt);
    conv_bias_kernel<<<OH * XT, 256, 0, stream>>>(in, wt, bias, out);
}